// Round 5
// baseline (205.803 us; speedup 1.0000x reference)
//
#include <hip/hip_runtime.h>
#include <hip/hip_bf16.h>
#include <cstdint>

// Problem constants (B=2, S=2048, DIM=1024, H=16, KVH=4, HD=64, WINDOW=256)
#define S_LEN 2048
#define QKV_COLS 1536   // 1024 q | 256 k | 256 v

typedef __bf16 bf16_t;
typedef bf16_t bf16x8 __attribute__((ext_vector_type(8)));
typedef bf16_t bf16x4 __attribute__((ext_vector_type(4)));
typedef float f32x4 __attribute__((ext_vector_type(4)));

typedef __attribute__((address_space(1))) void as1_void;
typedef __attribute__((address_space(3))) void as3_void;

__device__ __forceinline__ void async_load16(const void* g, void* lds) {
  __builtin_amdgcn_global_load_lds(
      (as1_void*)(uintptr_t)g,
      (as3_void*)(uint32_t)(uintptr_t)lds,
      16, 0, 0);
}

// ---------------- f32 -> bf16 convert; Wo gets pair_mix premixed ------------
// out = y' @ Wo^T with y'[p,o] = sum_i pm[p,o,i] y[p,i]
//     = y @ Wo'^T with Wo'[:, (2p+i)*64+d] = sum_o pm[p,o,i] * Wo[:, (2p+o)*64+d]
__global__ __launch_bounds__(256) void convert_all(
    const float4* __restrict__ x, const float4* __restrict__ wq,
    const float4* __restrict__ wk, const float4* __restrict__ wv,
    const float4* __restrict__ wo, const float* __restrict__ pm,
    bf16x4* __restrict__ xb, bf16x4* __restrict__ wqkvb, bf16x4* __restrict__ wob) {
  int u = blockIdx.x * 256 + threadIdx.x;
  if (u >= 1441792) {                       // Wo premix region
    int off = u - 1441792;                  // float4 index into 1024x1024
    int flat = off * 4;
    int row = flat >> 10, colf = flat & 1023;  // col = h*64 + d, 4-aligned
    int col2p = colf & ~64;                 // head-pair base column (bit6 = h&1)
    int p = colf >> 7, ii = (colf >> 6) & 1;
    float4 a = wo[(row * 1024 + col2p) >> 2];
    float4 bq = wo[(row * 1024 + (col2p | 64)) >> 2];
    float m0v = pm[p * 4 + ii], m1v = pm[p * 4 + 2 + ii];
    bf16x4 o4;
    o4[0] = (bf16_t)(m0v * a.x + m1v * bq.x);
    o4[1] = (bf16_t)(m0v * a.y + m1v * bq.y);
    o4[2] = (bf16_t)(m0v * a.z + m1v * bq.z);
    o4[3] = (bf16_t)(m0v * a.w + m1v * bq.w);
    wob[off] = o4;
    return;
  }
  const float4* src; bf16x4* dst; int off;
  if (u < 1048576)      { src = x;  dst = xb;             off = u; }
  else if (u < 1310720) { src = wq; dst = wqkvb;          off = u - 1048576; }
  else if (u < 1376256) { src = wk; dst = wqkvb + 262144; off = u - 1310720; }
  else                  { src = wv; dst = wqkvb + 327680; off = u - 1376256; }
  float4 f = src[off];
  bf16x4 o;
  o[0] = (bf16_t)f.x; o[1] = (bf16_t)f.y; o[2] = (bf16_t)f.z; o[3] = (bf16_t)f.w;
  dst[off] = o;
}

// ---------------- QKV GEMM (64x128 tile) + RMSNorm/RoPE/gain + V-transpose --
// C[M,1536] = A[M,1024] * B[1536,1024]^T. grid (12, 64) = 768 blocks (3/CU).
// Wave = 32 rows x 64 cols (one full head per row -> epilogue local to wave).
__global__ __launch_bounds__(256) void gemm_qkv(
    const bf16_t* __restrict__ A, const bf16_t* __restrict__ B,
    bf16_t* __restrict__ C, bf16_t* __restrict__ vt,
    const float* __restrict__ q_gain, int N, int K) {
  __shared__ bf16_t As[64 * 32];
  __shared__ bf16_t Bs[128 * 32];
  const int tid = threadIdx.x;
  const int lane = tid & 63;
  const int w = tid >> 6;
  const int wm = (w & 1) << 5, wn = (w >> 1) << 6;
  const int m0 = blockIdx.y << 6, n0 = blockIdx.x << 7;
  const int fidx = lane & 15, quad = lane >> 4;
  f32x4 acc[2][4] = {};
  const int cA = tid, cB0 = tid, cB1 = tid + 256;
  const bf16_t* Ag  = A + (size_t)(m0 + (cA >> 2)) * K + (cA & 3) * 8;
  const bf16_t* Bg0 = B + (size_t)(n0 + (cB0 >> 2)) * K + (cB0 & 3) * 8;
  const bf16_t* Bg1 = B + (size_t)(n0 + (cB1 >> 2)) * K + (cB1 & 3) * 8;
  for (int kt = 0; kt < K; kt += 32) {
    __syncthreads();
    async_load16(Ag + kt, As + cA * 8);
    async_load16(Bg0 + kt, Bs + cB0 * 8);
    async_load16(Bg1 + kt, Bs + cB1 * 8);
    __syncthreads();
    bf16x8 af[2], bfr[4];
#pragma unroll
    for (int i = 0; i < 2; i++)
      af[i] = *(const bf16x8*)(As + (wm + i * 16 + fidx) * 32 + quad * 8);
#pragma unroll
    for (int i = 0; i < 4; i++)
      bfr[i] = *(const bf16x8*)(Bs + (wn + i * 16 + fidx) * 32 + quad * 8);
#pragma unroll
    for (int mi = 0; mi < 2; mi++)
#pragma unroll
      for (int ni = 0; ni < 4; ni++)
        acc[mi][ni] = __builtin_amdgcn_mfma_f32_16x16x32_bf16(
            af[mi], bfr[ni], acc[mi][ni], 0, 0, 0);
  }
  const int hc0 = n0 + wn;        // head starting col (multiple of 64)
  if (hc0 >= 1280) {
    // ---- V: transposed store into vt[(b*4+g)*64+dh][s]
#pragma unroll
    for (int mi = 0; mi < 2; mi++)
#pragma unroll
      for (int ni = 0; ni < 4; ni++) {
        int cg = (hc0 - 1280) + ni * 16 + fidx;   // 0..255
        int g = cg >> 6, dh = cg & 63;
        int srow = m0 + wm + mi * 16 + quad * 4;  // first of 4 consecutive tokens
        int bb = srow >> 11, si = srow & (S_LEN - 1);
        bf16x4 pack;
#pragma unroll
        for (int r = 0; r < 4; r++) pack[r] = (bf16_t)acc[mi][ni][r];
        *(bf16x4*)(vt + ((size_t)((bb * 4 + g) * 64 + dh)) * S_LEN + si) = pack;
      }
    return;
  }
  // ---- q/k: RMSNorm + RoPE (+gain for q)
  float gain = 1.f;
  if (hc0 < 1024) gain = q_gain[hc0 >> 6] * 0.125f;  // fold softmax scale
#pragma unroll
  for (int mi = 0; mi < 2; mi++)
#pragma unroll
    for (int r = 0; r < 4; r++) {
      float ss = 0.f;
#pragma unroll
      for (int ni = 0; ni < 4; ni++) { float t = acc[mi][ni][r]; ss += t * t; }
#pragma unroll
      for (int off = 8; off >= 1; off >>= 1) ss += __shfl_xor(ss, off);
      float scl = rsqrtf(ss * (1.f / 64.f) + 1e-6f);
      int s = (m0 + wm + mi * 16 + quad * 4 + r) & (S_LEN - 1);
#pragma unroll
      for (int ni = 0; ni < 2; ni++) {
        float v1 = acc[mi][ni][r] * scl;
        float v2 = acc[mi][ni + 2][r] * scl;
        float fr = (float)(ni * 16 + fidx);
        float ang = (float)s * __expf(fr * -0.28782313662425575f);  // ln(1e4)/32
        float sn, cs;
        __sincosf(ang, &sn, &cs);
        acc[mi][ni][r]     = (v1 * cs + v2 * sn) * gain;
        acc[mi][ni + 2][r] = (-v1 * sn + v2 * cs) * gain;
      }
    }
#pragma unroll
  for (int mi = 0; mi < 2; mi++)
#pragma unroll
    for (int ni = 0; ni < 4; ni++)
#pragma unroll
      for (int r = 0; r < 4; r++) {
        int gr = m0 + wm + mi * 16 + quad * 4 + r;
        int gc = n0 + wn + ni * 16 + fidx;
        C[(size_t)gr * N + gc] = (bf16_t)acc[mi][ni][r];
      }
}

// ---------------- out-proj GEMM (64x128 tile, f32 out): C = A * B^T ---------
// grid (8, 64) = 512 blocks (2/CU).
__global__ __launch_bounds__(256) void gemm_bt_f32(
    const bf16_t* __restrict__ A, const bf16_t* __restrict__ B,
    float* __restrict__ C, int N, int K) {
  __shared__ bf16_t As[64 * 32];
  __shared__ bf16_t Bs[128 * 32];
  const int tid = threadIdx.x;
  const int lane = tid & 63;
  const int w = tid >> 6;
  const int wm = (w & 1) << 5, wn = (w >> 1) << 6;
  const int m0 = blockIdx.y << 6, n0 = blockIdx.x << 7;
  const int fidx = lane & 15, quad = lane >> 4;
  f32x4 acc[2][4] = {};
  const int cA = tid, cB0 = tid, cB1 = tid + 256;
  const bf16_t* Ag  = A + (size_t)(m0 + (cA >> 2)) * K + (cA & 3) * 8;
  const bf16_t* Bg0 = B + (size_t)(n0 + (cB0 >> 2)) * K + (cB0 & 3) * 8;
  const bf16_t* Bg1 = B + (size_t)(n0 + (cB1 >> 2)) * K + (cB1 & 3) * 8;
  for (int kt = 0; kt < K; kt += 32) {
    __syncthreads();
    async_load16(Ag + kt, As + cA * 8);
    async_load16(Bg0 + kt, Bs + cB0 * 8);
    async_load16(Bg1 + kt, Bs + cB1 * 8);
    __syncthreads();
    bf16x8 af[2], bfr[4];
#pragma unroll
    for (int i = 0; i < 2; i++)
      af[i] = *(const bf16x8*)(As + (wm + i * 16 + fidx) * 32 + quad * 8);
#pragma unroll
    for (int i = 0; i < 4; i++)
      bfr[i] = *(const bf16x8*)(Bs + (wn + i * 16 + fidx) * 32 + quad * 8);
#pragma unroll
    for (int mi = 0; mi < 2; mi++)
#pragma unroll
      for (int ni = 0; ni < 4; ni++)
        acc[mi][ni] = __builtin_amdgcn_mfma_f32_16x16x32_bf16(
            af[mi], bfr[ni], acc[mi][ni], 0, 0, 0);
  }
#pragma unroll
  for (int mi = 0; mi < 2; mi++)
#pragma unroll
    for (int ni = 0; ni < 4; ni++)
#pragma unroll
      for (int r = 0; r < 4; r++) {
        int gr = m0 + wm + mi * 16 + quad * 4 + r;
        int gc = n0 + wn + ni * 16 + fidx;
        C[(size_t)gr * N + gc] = acc[mi][ni][r];
      }
}

// ---------------- MFMA flash attention (no pair mix; premixed into Wo) ------
// 1D grid 1024 with XCD swizzle: consecutive-q tiles share a K window on one
// XCD's L2. Block = 4 waves = 4 heads of one kv-group; 64-key chunks with
// one-chunk K register prefetch (K latency hidden under prev chunk's softmax).
#define PST 72  // P row stride (bf16): 144B keeps ds_read_b128 16B-aligned
__global__ __launch_bounds__(256) void attn_mfma(
    const bf16_t* __restrict__ qkv, const bf16_t* __restrict__ vt,
    bf16_t* __restrict__ yb) {
  __shared__ bf16_t plds[4][16 * PST];
  const int tid = threadIdx.x, lane = tid & 63, w = tid >> 6;
  const int col = lane & 15, quad = lane >> 4;
  // XCD swizzle: n&7 = round-robin XCD slot; give each slot a contiguous
  // 16-q-tile span across all (g,b) so the K window stays in one XCD L2.
  const int n = blockIdx.x;
  const int j = n & 7, i = n >> 3;
  const int gb = i & 7, qt = j * 16 + (i >> 3);
  const int g = gb & 3, b = gb >> 2;
  const int q0 = qt * 16;
  const int h = g * 4 + w;

  const bf16_t* qb = qkv + ((size_t)b * S_LEN + q0 + col) * QKV_COLS + h * 64 + quad * 8;
  bf16x8 qf0 = *(const bf16x8*)qb;
  bf16x8 qf1 = *(const bf16x8*)(qb + 32);

  const bf16_t* kbase = qkv + (size_t)b * S_LEN * QKV_COLS + 1024 + g * 64 + quad * 8;
  const bf16_t* vbase = vt + ((size_t)((b * 4 + g) * 64) + col) * S_LEN + quad * 8;

  f32x4 o[4] = {};
  float m[4], l[4];
#pragma unroll
  for (int r = 0; r < 4; r++) { m[r] = -1e30f; l[r] = 0.f; }

  const int c_lo = max(0, (q0 - 255) >> 6);
  const int c_hi = (q0 + 15) >> 6;

  bf16x8 kf[2][4][2];
  auto load_k = [&](int k0d, bf16x8 (*dst)[2]) {
#pragma unroll
    for (int nt = 0; nt < 4; nt++) {
      const bf16_t* kp = kbase + (size_t)(k0d + nt * 16 + col) * QKV_COLS;
      dst[nt][0] = *(const bf16x8*)kp;
      dst[nt][1] = *(const bf16x8*)(kp + 32);
    }
  };
  load_k(c_lo * 64, kf[0]);

  for (int c = c_lo; c <= c_hi; c++) {
    const int k0 = c * 64;
    const int cur = (c - c_lo) & 1;
    if (c < c_hi) load_k(k0 + 64, kf[cur ^ 1]);   // prefetch next chunk's K
    // V loads issued before softmax: latency covered by VALU phase
    bf16x8 vf[4][2];
#pragma unroll
    for (int nt2 = 0; nt2 < 4; nt2++) {
      const bf16_t* vp = vbase + (size_t)(nt2 * 16) * S_LEN + k0;
      vf[nt2][0] = *(const bf16x8*)vp;
      vf[nt2][1] = *(const bf16x8*)(vp + 32);
    }
    // ---- scores S[16q x 64k]
    f32x4 s4[4];
#pragma unroll
    for (int nt = 0; nt < 4; nt++) {
      f32x4 a = {};
      a = __builtin_amdgcn_mfma_f32_16x16x32_bf16(qf0, kf[cur][nt][0], a, 0, 0, 0);
      a = __builtin_amdgcn_mfma_f32_16x16x32_bf16(qf1, kf[cur][nt][1], a, 0, 0, 0);
      s4[nt] = a;
    }
    const bool needmask = (k0 + 63 > q0) || (k0 < q0 - 240);  // wave-uniform
    float alpha[4], psum[4];
    if (needmask) {
#pragma unroll
      for (int r = 0; r < 4; r++) {
        int q = q0 + quad * 4 + r;
#pragma unroll
        for (int nt = 0; nt < 4; nt++) {
          int k = k0 + nt * 16 + col;
          bool valid = (k <= q) && (q - k < 256);
          s4[nt][r] = valid ? s4[nt][r] : -1e30f;
        }
        float v = fmaxf(fmaxf(s4[0][r], s4[1][r]), fmaxf(s4[2][r], s4[3][r]));
#pragma unroll
        for (int off = 8; off >= 1; off >>= 1) v = fmaxf(v, __shfl_xor(v, off));
        float mn = fmaxf(m[r], v);
        alpha[r] = __expf(m[r] - mn);
        m[r] = mn;
        float ps = 0.f;
#pragma unroll
        for (int nt = 0; nt < 4; nt++) {
          float sv = s4[nt][r];
          float p = (sv > -1e29f) ? __expf(sv - m[r]) : 0.f;
          ps += p;
          plds[w][(quad * 4 + r) * PST + nt * 16 + col] = (bf16_t)p;
        }
        psum[r] = ps;
      }
    } else {
#pragma unroll
      for (int r = 0; r < 4; r++) {
        float v = fmaxf(fmaxf(s4[0][r], s4[1][r]), fmaxf(s4[2][r], s4[3][r]));
#pragma unroll
        for (int off = 8; off >= 1; off >>= 1) v = fmaxf(v, __shfl_xor(v, off));
        float mn = fmaxf(m[r], v);
        alpha[r] = __expf(m[r] - mn);
        m[r] = mn;
        float ps = 0.f;
#pragma unroll
        for (int nt = 0; nt < 4; nt++) {
          float p = __expf(s4[nt][r] - m[r]);
          ps += p;
          plds[w][(quad * 4 + r) * PST + nt * 16 + col] = (bf16_t)p;
        }
        psum[r] = ps;
      }
    }
#pragma unroll
    for (int r = 0; r < 4; r++) {
      float v = psum[r];
#pragma unroll
      for (int off = 8; off >= 1; off >>= 1) v += __shfl_xor(v, off);
      l[r] = l[r] * alpha[r] + v;
#pragma unroll
      for (int nt2 = 0; nt2 < 4; nt2++) o[nt2][r] *= alpha[r];
    }
    // ---- PV
    asm volatile("s_waitcnt lgkmcnt(0)" ::: "memory");
    bf16x8 pf0 = *(const bf16x8*)(plds[w] + col * PST + quad * 8);
    bf16x8 pf1 = *(const bf16x8*)(plds[w] + col * PST + 32 + quad * 8);
#pragma unroll
    for (int nt2 = 0; nt2 < 4; nt2++) {
      o[nt2] = __builtin_amdgcn_mfma_f32_16x16x32_bf16(pf0, vf[nt2][0], o[nt2], 0, 0, 0);
      o[nt2] = __builtin_amdgcn_mfma_f32_16x16x32_bf16(pf1, vf[nt2][1], o[nt2], 0, 0, 0);
    }
  }
  // ---- normalize + direct stores (no pair mix needed)
#pragma unroll
  for (int r = 0; r < 4; r++) {
    float il = 1.f / l[r];
    bf16_t* yp = yb + ((size_t)b * S_LEN + q0 + quad * 4 + r) * 1024 + h * 64 + col;
#pragma unroll
    for (int nt2 = 0; nt2 < 4; nt2++)
      yp[nt2 * 16] = (bf16_t)(o[nt2][r] * il);
  }
}

extern "C" void kernel_launch(void* const* d_in, const int* in_sizes, int n_in,
                              void* d_out, int out_size, void* d_ws, size_t ws_size,
                              hipStream_t stream) {
  const float* x        = (const float*)d_in[0];
  const float* Wq       = (const float*)d_in[1];
  const float* Wk       = (const float*)d_in[2];
  const float* Wv       = (const float*)d_in[3];
  const float* Wo       = (const float*)d_in[4];
  const float* q_gain   = (const float*)d_in[5];
  const float* pair_mix = (const float*)d_in[6];
  float* out = (float*)d_out;

  bf16_t* ws    = (bf16_t*)d_ws;
  bf16_t* xb    = ws;                   // 4096*1024
  bf16_t* wqkvb = xb + 4096 * 1024;     // 1536*1024
  bf16_t* wob   = wqkvb + 1536 * 1024;  // 1024*1024 (premixed)
  bf16_t* qkvb  = wob + 1024 * 1024;    // 4096*1536
  bf16_t* yb    = qkvb + 4096 * 1536;   // 4096*1024
  bf16_t* vt    = yb + 4096 * 1024;     // 8*64*2048 (total ~36.7 MB)

  convert_all<<<6656, 256, 0, stream>>>(
      (const float4*)x, (const float4*)Wq, (const float4*)Wk, (const float4*)Wv,
      (const float4*)Wo, pair_mix, (bf16x4*)xb, (bf16x4*)wqkvb, (bf16x4*)wob);
  gemm_qkv<<<dim3(12, 64), 256, 0, stream>>>(xb, wqkvb, qkvb, vt, q_gain, 1536, 1024);
  attn_mfma<<<1024, 256, 0, stream>>>(qkvb, vt, yb);
  gemm_bt_f32<<<dim3(8, 64), 256, 0, stream>>>(yb, wob, out, 1024, 1024);
}

// Round 6
// 163.398 us; speedup vs baseline: 1.2595x; 1.2595x over previous
//
#include <hip/hip_runtime.h>
#include <hip/hip_bf16.h>
#include <cstdint>

// Problem constants (B=2, S=2048, DIM=1024, H=16, KVH=4, HD=64, WINDOW=256)
#define S_LEN 2048
#define QKV_COLS 1536   // 1024 q | 256 k | 256 v

typedef __bf16 bf16_t;
typedef bf16_t bf16x8 __attribute__((ext_vector_type(8)));
typedef bf16_t bf16x4 __attribute__((ext_vector_type(4)));
typedef float f32x4 __attribute__((ext_vector_type(4)));

typedef __attribute__((address_space(1))) void as1_void;
typedef __attribute__((address_space(3))) void as3_void;

__device__ __forceinline__ void async_load16(const void* g, void* lds) {
  __builtin_amdgcn_global_load_lds(
      (as1_void*)(uintptr_t)g,
      (as3_void*)(uint32_t)(uintptr_t)lds,
      16, 0, 0);
}

// ---------------- f32 -> bf16 convert; Wo gets pair_mix premixed ------------
// out = y' @ Wo^T with y'[p,o] = sum_i pm[p,o,i] y[p,i]
//     = y @ Wo'^T with Wo'[:, (2p+i)*64+d] = sum_o pm[p,o,i] * Wo[:, (2p+o)*64+d]
__global__ __launch_bounds__(256) void convert_all(
    const float4* __restrict__ x, const float4* __restrict__ wq,
    const float4* __restrict__ wk, const float4* __restrict__ wv,
    const float4* __restrict__ wo, const float* __restrict__ pm,
    bf16x4* __restrict__ xb, bf16x4* __restrict__ wqkvb, bf16x4* __restrict__ wob) {
  int u = blockIdx.x * 256 + threadIdx.x;
  if (u >= 1441792) {                       // Wo premix region
    int off = u - 1441792;                  // float4 index into 1024x1024
    int flat = off * 4;
    int row = flat >> 10, colf = flat & 1023;  // col = h*64 + d, 4-aligned
    int col2p = colf & ~64;                 // head-pair base column (bit6 = h&1)
    int p = colf >> 7, ii = (colf >> 6) & 1;
    float4 a = wo[(row * 1024 + col2p) >> 2];
    float4 bq = wo[(row * 1024 + (col2p | 64)) >> 2];
    float m0v = pm[p * 4 + ii], m1v = pm[p * 4 + 2 + ii];
    bf16x4 o4;
    o4[0] = (bf16_t)(m0v * a.x + m1v * bq.x);
    o4[1] = (bf16_t)(m0v * a.y + m1v * bq.y);
    o4[2] = (bf16_t)(m0v * a.z + m1v * bq.z);
    o4[3] = (bf16_t)(m0v * a.w + m1v * bq.w);
    wob[off] = o4;
    return;
  }
  const float4* src; bf16x4* dst; int off;
  if (u < 1048576)      { src = x;  dst = xb;             off = u; }
  else if (u < 1310720) { src = wq; dst = wqkvb;          off = u - 1048576; }
  else if (u < 1376256) { src = wk; dst = wqkvb + 262144; off = u - 1310720; }
  else                  { src = wv; dst = wqkvb + 327680; off = u - 1376256; }
  float4 f = src[off];
  bf16x4 o;
  o[0] = (bf16_t)f.x; o[1] = (bf16_t)f.y; o[2] = (bf16_t)f.z; o[3] = (bf16_t)f.w;
  dst[off] = o;
}

// ---------------- QKV GEMM (64x128 tile) + RMSNorm/RoPE/gain + V-transpose --
// C[M,1536] = A[M,1024] * B[1536,1024]^T. grid (12, 64) = 768 blocks (3/CU).
__global__ __launch_bounds__(256) void gemm_qkv(
    const bf16_t* __restrict__ A, const bf16_t* __restrict__ B,
    bf16_t* __restrict__ C, bf16_t* __restrict__ vt,
    const float* __restrict__ q_gain, int N, int K) {
  __shared__ bf16_t As[64 * 32];
  __shared__ bf16_t Bs[128 * 32];
  const int tid = threadIdx.x;
  const int lane = tid & 63;
  const int w = tid >> 6;
  const int wm = (w & 1) << 5, wn = (w >> 1) << 6;
  const int m0 = blockIdx.y << 6, n0 = blockIdx.x << 7;
  const int fidx = lane & 15, quad = lane >> 4;
  f32x4 acc[2][4] = {};
  const int cA = tid, cB0 = tid, cB1 = tid + 256;
  const bf16_t* Ag  = A + (size_t)(m0 + (cA >> 2)) * K + (cA & 3) * 8;
  const bf16_t* Bg0 = B + (size_t)(n0 + (cB0 >> 2)) * K + (cB0 & 3) * 8;
  const bf16_t* Bg1 = B + (size_t)(n0 + (cB1 >> 2)) * K + (cB1 & 3) * 8;
  for (int kt = 0; kt < K; kt += 32) {
    __syncthreads();
    async_load16(Ag + kt, As + cA * 8);
    async_load16(Bg0 + kt, Bs + cB0 * 8);
    async_load16(Bg1 + kt, Bs + cB1 * 8);
    __syncthreads();
    bf16x8 af[2], bfr[4];
#pragma unroll
    for (int i = 0; i < 2; i++)
      af[i] = *(const bf16x8*)(As + (wm + i * 16 + fidx) * 32 + quad * 8);
#pragma unroll
    for (int i = 0; i < 4; i++)
      bfr[i] = *(const bf16x8*)(Bs + (wn + i * 16 + fidx) * 32 + quad * 8);
#pragma unroll
    for (int mi = 0; mi < 2; mi++)
#pragma unroll
      for (int ni = 0; ni < 4; ni++)
        acc[mi][ni] = __builtin_amdgcn_mfma_f32_16x16x32_bf16(
            af[mi], bfr[ni], acc[mi][ni], 0, 0, 0);
  }
  const int hc0 = n0 + wn;        // head starting col (multiple of 64)
  if (hc0 >= 1280) {
    // ---- V: transposed store into vt[(b*4+g)*64+dh][s]
#pragma unroll
    for (int mi = 0; mi < 2; mi++)
#pragma unroll
      for (int ni = 0; ni < 4; ni++) {
        int cg = (hc0 - 1280) + ni * 16 + fidx;   // 0..255
        int g = cg >> 6, dh = cg & 63;
        int srow = m0 + wm + mi * 16 + quad * 4;  // first of 4 consecutive tokens
        int bb = srow >> 11, si = srow & (S_LEN - 1);
        bf16x4 pack;
#pragma unroll
        for (int r = 0; r < 4; r++) pack[r] = (bf16_t)acc[mi][ni][r];
        *(bf16x4*)(vt + ((size_t)((bb * 4 + g) * 64 + dh)) * S_LEN + si) = pack;
      }
    return;
  }
  // ---- q/k: RMSNorm + RoPE (+gain for q)
  float gain = 1.f;
  if (hc0 < 1024) gain = q_gain[hc0 >> 6] * 0.125f;  // fold softmax scale
#pragma unroll
  for (int mi = 0; mi < 2; mi++)
#pragma unroll
    for (int r = 0; r < 4; r++) {
      float ss = 0.f;
#pragma unroll
      for (int ni = 0; ni < 4; ni++) { float t = acc[mi][ni][r]; ss += t * t; }
#pragma unroll
      for (int off = 8; off >= 1; off >>= 1) ss += __shfl_xor(ss, off);
      float scl = rsqrtf(ss * (1.f / 64.f) + 1e-6f);
      int s = (m0 + wm + mi * 16 + quad * 4 + r) & (S_LEN - 1);
#pragma unroll
      for (int ni = 0; ni < 2; ni++) {
        float v1 = acc[mi][ni][r] * scl;
        float v2 = acc[mi][ni + 2][r] * scl;
        float fr = (float)(ni * 16 + fidx);
        float ang = (float)s * __expf(fr * -0.28782313662425575f);  // ln(1e4)/32
        float sn, cs;
        __sincosf(ang, &sn, &cs);
        acc[mi][ni][r]     = (v1 * cs + v2 * sn) * gain;
        acc[mi][ni + 2][r] = (-v1 * sn + v2 * cs) * gain;
      }
    }
#pragma unroll
  for (int mi = 0; mi < 2; mi++)
#pragma unroll
    for (int ni = 0; ni < 4; ni++)
#pragma unroll
      for (int r = 0; r < 4; r++) {
        int gr = m0 + wm + mi * 16 + quad * 4 + r;
        int gc = n0 + wn + ni * 16 + fidx;
        C[(size_t)gr * N + gc] = (bf16_t)acc[mi][ni][r];
      }
}

// ---------------- out-proj GEMM (64x128 tile, f32 out): C = A * B^T ---------
__global__ __launch_bounds__(256) void gemm_bt_f32(
    const bf16_t* __restrict__ A, const bf16_t* __restrict__ B,
    float* __restrict__ C, int N, int K) {
  __shared__ bf16_t As[64 * 32];
  __shared__ bf16_t Bs[128 * 32];
  const int tid = threadIdx.x;
  const int lane = tid & 63;
  const int w = tid >> 6;
  const int wm = (w & 1) << 5, wn = (w >> 1) << 6;
  const int m0 = blockIdx.y << 6, n0 = blockIdx.x << 7;
  const int fidx = lane & 15, quad = lane >> 4;
  f32x4 acc[2][4] = {};
  const int cA = tid, cB0 = tid, cB1 = tid + 256;
  const bf16_t* Ag  = A + (size_t)(m0 + (cA >> 2)) * K + (cA & 3) * 8;
  const bf16_t* Bg0 = B + (size_t)(n0 + (cB0 >> 2)) * K + (cB0 & 3) * 8;
  const bf16_t* Bg1 = B + (size_t)(n0 + (cB1 >> 2)) * K + (cB1 & 3) * 8;
  for (int kt = 0; kt < K; kt += 32) {
    __syncthreads();
    async_load16(Ag + kt, As + cA * 8);
    async_load16(Bg0 + kt, Bs + cB0 * 8);
    async_load16(Bg1 + kt, Bs + cB1 * 8);
    __syncthreads();
    bf16x8 af[2], bfr[4];
#pragma unroll
    for (int i = 0; i < 2; i++)
      af[i] = *(const bf16x8*)(As + (wm + i * 16 + fidx) * 32 + quad * 8);
#pragma unroll
    for (int i = 0; i < 4; i++)
      bfr[i] = *(const bf16x8*)(Bs + (wn + i * 16 + fidx) * 32 + quad * 8);
#pragma unroll
    for (int mi = 0; mi < 2; mi++)
#pragma unroll
      for (int ni = 0; ni < 4; ni++)
        acc[mi][ni] = __builtin_amdgcn_mfma_f32_16x16x32_bf16(
            af[mi], bfr[ni], acc[mi][ni], 0, 0, 0);
  }
#pragma unroll
  for (int mi = 0; mi < 2; mi++)
#pragma unroll
    for (int ni = 0; ni < 4; ni++)
#pragma unroll
      for (int r = 0; r < 4; r++) {
        int gr = m0 + wm + mi * 16 + quad * 4 + r;
        int gc = n0 + wn + ni * 16 + fidx;
        C[(size_t)gr * N + gc] = acc[mi][ni][r];
      }
}

// ---------------- MFMA flash attention (pair mix premixed into Wo) ----------
// block = (b, kv group g, 32-query tile). 4 waves = 4 q heads of the group.
// Each wave: two 16-q M-tiles sharing every 32-key K/V chunk fetch.
// Epilogue: wave-local bf16 LDS stage -> coalesced bf16x8 stores (R5's direct
// scalar stores caused 20x HBM write amplification — partial-line RMW).
#define PST 40  // P row stride: 80 B = 5*16 B, ds_read_b128 aligned
#define OST 72  // O stage row stride: 144 B = 9*16 B, aligned
__global__ __launch_bounds__(256) void attn_mfma(
    const bf16_t* __restrict__ qkv, const bf16_t* __restrict__ vt,
    bf16_t* __restrict__ yb) {
  __shared__ bf16_t plds[4][16 * PST];
  __shared__ bf16_t ob[4][32 * OST];
  const int tid = threadIdx.x, lane = tid & 63, w = tid >> 6;
  const int col = lane & 15, quad = lane >> 4;
  const int q0 = blockIdx.x * 32, g = blockIdx.y, b = blockIdx.z;
  const int h = g * 4 + w;

  bf16x8 qf[2][2];
#pragma unroll
  for (int t = 0; t < 2; t++) {
    const bf16_t* qb =
        qkv + ((size_t)b * S_LEN + q0 + t * 16 + col) * QKV_COLS + h * 64 + quad * 8;
    qf[t][0] = *(const bf16x8*)qb;
    qf[t][1] = *(const bf16x8*)(qb + 32);
  }
  const bf16_t* kbase = qkv + (size_t)b * S_LEN * QKV_COLS + 1024 + g * 64 + quad * 8;
  const bf16_t* vbase = vt + ((size_t)((b * 4 + g) * 64) + col) * S_LEN + quad * 8;

  f32x4 o[2][4] = {};
  float m[2][4], l[2][4];
#pragma unroll
  for (int t = 0; t < 2; t++)
#pragma unroll
    for (int r = 0; r < 4; r++) { m[t][r] = -1e30f; l[t][r] = 0.f; }

  const int c_lo = max(0, (q0 - 255) >> 5);
  const int c_hi = (q0 + 31) >> 5;
  for (int c = c_lo; c <= c_hi; c++) {
    const int k0 = c * 32;
    bf16x8 kf[2][2];
#pragma unroll
    for (int nt = 0; nt < 2; nt++) {
      const bf16_t* kp = kbase + (size_t)(k0 + nt * 16 + col) * QKV_COLS;
      kf[nt][0] = *(const bf16x8*)kp;
      kf[nt][1] = *(const bf16x8*)(kp + 32);
    }
    bf16x8 vf[4];
#pragma unroll
    for (int nt2 = 0; nt2 < 4; nt2++)
      vf[nt2] = *(const bf16x8*)(vbase + (size_t)(nt2 * 16) * S_LEN + k0);

#pragma unroll
    for (int t = 0; t < 2; t++) {
      const int qt0 = q0 + t * 16;
      if (k0 > qt0 + 15) continue;          // fully above diagonal for this tile
      f32x4 s[2];
#pragma unroll
      for (int nt = 0; nt < 2; nt++) {
        f32x4 a = {};
        a = __builtin_amdgcn_mfma_f32_16x16x32_bf16(qf[t][0], kf[nt][0], a, 0, 0, 0);
        a = __builtin_amdgcn_mfma_f32_16x16x32_bf16(qf[t][1], kf[nt][1], a, 0, 0, 0);
        s[nt] = a;
      }
      const bool needmask = (k0 + 31 > qt0) || (k0 < qt0 - 224);  // wave-uniform
      float alpha[4], psum[4];
#pragma unroll
      for (int r = 0; r < 4; r++) {
        if (needmask) {
          int q = qt0 + quad * 4 + r;
#pragma unroll
          for (int nt = 0; nt < 2; nt++) {
            int k = k0 + nt * 16 + col;
            bool valid = (k <= q) && (q - k < 256);
            s[nt][r] = valid ? s[nt][r] : -1e30f;
          }
        }
        float v = fmaxf(s[0][r], s[1][r]);
#pragma unroll
        for (int off = 8; off >= 1; off >>= 1) v = fmaxf(v, __shfl_xor(v, off));
        float mn = fmaxf(m[t][r], v);
        alpha[r] = __expf(m[t][r] - mn);
        m[t][r] = mn;
        float ps = 0.f;
#pragma unroll
        for (int nt = 0; nt < 2; nt++) {
          float sv = s[nt][r];
          float p = (sv > -1e29f) ? __expf(sv - m[t][r]) : 0.f;
          ps += p;
          plds[w][(quad * 4 + r) * PST + nt * 16 + col] = (bf16_t)p;
        }
        psum[r] = ps;
      }
#pragma unroll
      for (int r = 0; r < 4; r++) {
        float v = psum[r];
#pragma unroll
        for (int off = 8; off >= 1; off >>= 1) v += __shfl_xor(v, off);
        l[t][r] = l[t][r] * alpha[r] + v;
#pragma unroll
        for (int nt2 = 0; nt2 < 4; nt2++) o[t][nt2][r] *= alpha[r];
      }
      asm volatile("s_waitcnt lgkmcnt(0)" ::: "memory");
      bf16x8 pf = *(const bf16x8*)(plds[w] + col * PST + quad * 8);
#pragma unroll
      for (int nt2 = 0; nt2 < 4; nt2++)
        o[t][nt2] = __builtin_amdgcn_mfma_f32_16x16x32_bf16(pf, vf[nt2], o[t][nt2], 0, 0, 0);
    }
  }
  // ---- normalize -> wave-local bf16 LDS stage -> coalesced stores
#pragma unroll
  for (int t = 0; t < 2; t++)
#pragma unroll
    for (int r = 0; r < 4; r++) {
      float il = 1.f / l[t][r];
      int row = t * 16 + quad * 4 + r;
#pragma unroll
      for (int nt2 = 0; nt2 < 4; nt2++)
        ob[w][row * OST + nt2 * 16 + col] = (bf16_t)(o[t][nt2][r] * il);
    }
  asm volatile("s_waitcnt lgkmcnt(0)" ::: "memory");
#pragma unroll
  for (int it = 0; it < 4; it++) {
    int row = it * 8 + (lane >> 3);       // 0..31
    int d0 = (lane & 7) * 8;
    bf16x8 v8 = *(const bf16x8*)(ob[w] + row * OST + d0);
    *(bf16x8*)(yb + ((size_t)b * S_LEN + q0 + row) * 1024 + h * 64 + d0) = v8;
  }
}

extern "C" void kernel_launch(void* const* d_in, const int* in_sizes, int n_in,
                              void* d_out, int out_size, void* d_ws, size_t ws_size,
                              hipStream_t stream) {
  const float* x        = (const float*)d_in[0];
  const float* Wq       = (const float*)d_in[1];
  const float* Wk       = (const float*)d_in[2];
  const float* Wv       = (const float*)d_in[3];
  const float* Wo       = (const float*)d_in[4];
  const float* q_gain   = (const float*)d_in[5];
  const float* pair_mix = (const float*)d_in[6];
  float* out = (float*)d_out;

  bf16_t* ws    = (bf16_t*)d_ws;
  bf16_t* xb    = ws;                   // 4096*1024
  bf16_t* wqkvb = xb + 4096 * 1024;     // 1536*1024
  bf16_t* wob   = wqkvb + 1536 * 1024;  // 1024*1024 (premixed)
  bf16_t* qkvb  = wob + 1024 * 1024;    // 4096*1536
  bf16_t* yb    = qkvb + 4096 * 1536;   // 4096*1024
  bf16_t* vt    = yb + 4096 * 1024;     // 8*64*2048 (total ~36.7 MB)

  convert_all<<<6656, 256, 0, stream>>>(
      (const float4*)x, (const float4*)Wq, (const float4*)Wk, (const float4*)Wv,
      (const float4*)Wo, pair_mix, (bf16x4*)xb, (bf16x4*)wqkvb, (bf16x4*)wob);
  gemm_qkv<<<dim3(12, 64), 256, 0, stream>>>(xb, wqkvb, qkvb, vt, q_gain, 1536, 1024);
  attn_mfma<<<dim3(64, 4, 2), 256, 0, stream>>>(qkvb, vt, yb);
  gemm_bt_f32<<<dim3(8, 64), 256, 0, stream>>>(yb, wob, out, 1024, 1024);
}

// Round 7
// 154.246 us; speedup vs baseline: 1.3343x; 1.0593x over previous
//
#include <hip/hip_runtime.h>
#include <hip/hip_bf16.h>
#include <cstdint>

// Problem constants (B=2, S=2048, DIM=1024, H=16, KVH=4, HD=64, WINDOW=256)
#define S_LEN 2048
#define QKV_COLS 1536   // 1024 q | 256 k | 256 v

typedef __bf16 bf16_t;
typedef bf16_t bf16x8 __attribute__((ext_vector_type(8)));
typedef bf16_t bf16x4 __attribute__((ext_vector_type(4)));
typedef float f32x4 __attribute__((ext_vector_type(4)));

typedef __attribute__((address_space(1))) void as1_void;
typedef __attribute__((address_space(3))) void as3_void;

__device__ __forceinline__ void async_load16(const void* g, void* lds) {
  __builtin_amdgcn_global_load_lds(
      (as1_void*)(uintptr_t)g,
      (as3_void*)(uint32_t)(uintptr_t)lds,
      16, 0, 0);
}

// ---------------- f32 -> bf16 convert; Wo gets pair_mix premixed ------------
// out = y' @ Wo^T with y'[p,o] = sum_i pm[p,o,i] y[p,i]
//     = y @ Wo'^T with Wo'[:, (2p+i)*64+d] = sum_o pm[p,o,i] * Wo[:, (2p+o)*64+d]
__global__ __launch_bounds__(256) void convert_all(
    const float4* __restrict__ x, const float4* __restrict__ wq,
    const float4* __restrict__ wk, const float4* __restrict__ wv,
    const float4* __restrict__ wo, const float* __restrict__ pm,
    bf16x4* __restrict__ xb, bf16x4* __restrict__ wqkvb, bf16x4* __restrict__ wob) {
  int u = blockIdx.x * 256 + threadIdx.x;
  if (u >= 1441792) {                       // Wo premix region
    int off = u - 1441792;                  // float4 index into 1024x1024
    int flat = off * 4;
    int row = flat >> 10, colf = flat & 1023;  // col = h*64 + d, 4-aligned
    int col2p = colf & ~64;                 // head-pair base column (bit6 = h&1)
    int p = colf >> 7, ii = (colf >> 6) & 1;
    float4 a = wo[(row * 1024 + col2p) >> 2];
    float4 bq = wo[(row * 1024 + (col2p | 64)) >> 2];
    float m0v = pm[p * 4 + ii], m1v = pm[p * 4 + 2 + ii];
    bf16x4 o4;
    o4[0] = (bf16_t)(m0v * a.x + m1v * bq.x);
    o4[1] = (bf16_t)(m0v * a.y + m1v * bq.y);
    o4[2] = (bf16_t)(m0v * a.z + m1v * bq.z);
    o4[3] = (bf16_t)(m0v * a.w + m1v * bq.w);
    wob[off] = o4;
    return;
  }
  const float4* src; bf16x4* dst; int off;
  if (u < 1048576)      { src = x;  dst = xb;             off = u; }
  else if (u < 1310720) { src = wq; dst = wqkvb;          off = u - 1048576; }
  else if (u < 1376256) { src = wk; dst = wqkvb + 262144; off = u - 1310720; }
  else                  { src = wv; dst = wqkvb + 327680; off = u - 1376256; }
  float4 f = src[off];
  bf16x4 o;
  o[0] = (bf16_t)f.x; o[1] = (bf16_t)f.y; o[2] = (bf16_t)f.z; o[3] = (bf16_t)f.w;
  dst[off] = o;
}

// ---------------- QKV GEMM (64x128 tile) + RMSNorm/RoPE/gain + V-transpose --
// C[M,1536] = A[M,1024] * B[1536,1024]^T. grid (12, 64) = 768 blocks (3/CU).
__global__ __launch_bounds__(256) void gemm_qkv(
    const bf16_t* __restrict__ A, const bf16_t* __restrict__ B,
    bf16_t* __restrict__ C, bf16_t* __restrict__ vt,
    const float* __restrict__ q_gain, int N, int K) {
  __shared__ bf16_t As[64 * 32];
  __shared__ bf16_t Bs[128 * 32];
  const int tid = threadIdx.x;
  const int lane = tid & 63;
  const int w = tid >> 6;
  const int wm = (w & 1) << 5, wn = (w >> 1) << 6;
  const int m0 = blockIdx.y << 6, n0 = blockIdx.x << 7;
  const int fidx = lane & 15, quad = lane >> 4;
  f32x4 acc[2][4] = {};
  const int cA = tid, cB0 = tid, cB1 = tid + 256;
  const bf16_t* Ag  = A + (size_t)(m0 + (cA >> 2)) * K + (cA & 3) * 8;
  const bf16_t* Bg0 = B + (size_t)(n0 + (cB0 >> 2)) * K + (cB0 & 3) * 8;
  const bf16_t* Bg1 = B + (size_t)(n0 + (cB1 >> 2)) * K + (cB1 & 3) * 8;
  for (int kt = 0; kt < K; kt += 32) {
    __syncthreads();
    async_load16(Ag + kt, As + cA * 8);
    async_load16(Bg0 + kt, Bs + cB0 * 8);
    async_load16(Bg1 + kt, Bs + cB1 * 8);
    __syncthreads();
    bf16x8 af[2], bfr[4];
#pragma unroll
    for (int i = 0; i < 2; i++)
      af[i] = *(const bf16x8*)(As + (wm + i * 16 + fidx) * 32 + quad * 8);
#pragma unroll
    for (int i = 0; i < 4; i++)
      bfr[i] = *(const bf16x8*)(Bs + (wn + i * 16 + fidx) * 32 + quad * 8);
#pragma unroll
    for (int mi = 0; mi < 2; mi++)
#pragma unroll
      for (int ni = 0; ni < 4; ni++)
        acc[mi][ni] = __builtin_amdgcn_mfma_f32_16x16x32_bf16(
            af[mi], bfr[ni], acc[mi][ni], 0, 0, 0);
  }
  const int hc0 = n0 + wn;        // head starting col (multiple of 64)
  if (hc0 >= 1280) {
    // ---- V: transposed store into vt[(b*4+g)*64+dh][s]
#pragma unroll
    for (int mi = 0; mi < 2; mi++)
#pragma unroll
      for (int ni = 0; ni < 4; ni++) {
        int cg = (hc0 - 1280) + ni * 16 + fidx;   // 0..255
        int g = cg >> 6, dh = cg & 63;
        int srow = m0 + wm + mi * 16 + quad * 4;  // first of 4 consecutive tokens
        int bb = srow >> 11, si = srow & (S_LEN - 1);
        bf16x4 pack;
#pragma unroll
        for (int r = 0; r < 4; r++) pack[r] = (bf16_t)acc[mi][ni][r];
        *(bf16x4*)(vt + ((size_t)((bb * 4 + g) * 64 + dh)) * S_LEN + si) = pack;
      }
    return;
  }
  // ---- q/k: RMSNorm + RoPE (+gain for q)
  float gain = 1.f;
  if (hc0 < 1024) gain = q_gain[hc0 >> 6] * 0.125f;  // fold softmax scale
#pragma unroll
  for (int mi = 0; mi < 2; mi++)
#pragma unroll
    for (int r = 0; r < 4; r++) {
      float ss = 0.f;
#pragma unroll
      for (int ni = 0; ni < 4; ni++) { float t = acc[mi][ni][r]; ss += t * t; }
#pragma unroll
      for (int off = 8; off >= 1; off >>= 1) ss += __shfl_xor(ss, off);
      float scl = rsqrtf(ss * (1.f / 64.f) + 1e-6f);
      int s = (m0 + wm + mi * 16 + quad * 4 + r) & (S_LEN - 1);
#pragma unroll
      for (int ni = 0; ni < 2; ni++) {
        float v1 = acc[mi][ni][r] * scl;
        float v2 = acc[mi][ni + 2][r] * scl;
        float fr = (float)(ni * 16 + fidx);
        float ang = (float)s * __expf(fr * -0.28782313662425575f);  // ln(1e4)/32
        float sn, cs;
        __sincosf(ang, &sn, &cs);
        acc[mi][ni][r]     = (v1 * cs + v2 * sn) * gain;
        acc[mi][ni + 2][r] = (-v1 * sn + v2 * cs) * gain;
      }
    }
#pragma unroll
  for (int mi = 0; mi < 2; mi++)
#pragma unroll
    for (int ni = 0; ni < 4; ni++)
#pragma unroll
      for (int r = 0; r < 4; r++) {
        int gr = m0 + wm + mi * 16 + quad * 4 + r;
        int gc = n0 + wn + ni * 16 + fidx;
        C[(size_t)gr * N + gc] = (bf16_t)acc[mi][ni][r];
      }
}

// ---------------- out-proj GEMM (64x128 tile, f32 out): C = A * B^T ---------
__global__ __launch_bounds__(256) void gemm_bt_f32(
    const bf16_t* __restrict__ A, const bf16_t* __restrict__ B,
    float* __restrict__ C, int N, int K) {
  __shared__ bf16_t As[64 * 32];
  __shared__ bf16_t Bs[128 * 32];
  const int tid = threadIdx.x;
  const int lane = tid & 63;
  const int w = tid >> 6;
  const int wm = (w & 1) << 5, wn = (w >> 1) << 6;
  const int m0 = blockIdx.y << 6, n0 = blockIdx.x << 7;
  const int fidx = lane & 15, quad = lane >> 4;
  f32x4 acc[2][4] = {};
  const int cA = tid, cB0 = tid, cB1 = tid + 256;
  const bf16_t* Ag  = A + (size_t)(m0 + (cA >> 2)) * K + (cA & 3) * 8;
  const bf16_t* Bg0 = B + (size_t)(n0 + (cB0 >> 2)) * K + (cB0 & 3) * 8;
  const bf16_t* Bg1 = B + (size_t)(n0 + (cB1 >> 2)) * K + (cB1 & 3) * 8;
  for (int kt = 0; kt < K; kt += 32) {
    __syncthreads();
    async_load16(Ag + kt, As + cA * 8);
    async_load16(Bg0 + kt, Bs + cB0 * 8);
    async_load16(Bg1 + kt, Bs + cB1 * 8);
    __syncthreads();
    bf16x8 af[2], bfr[4];
#pragma unroll
    for (int i = 0; i < 2; i++)
      af[i] = *(const bf16x8*)(As + (wm + i * 16 + fidx) * 32 + quad * 8);
#pragma unroll
    for (int i = 0; i < 4; i++)
      bfr[i] = *(const bf16x8*)(Bs + (wn + i * 16 + fidx) * 32 + quad * 8);
#pragma unroll
    for (int mi = 0; mi < 2; mi++)
#pragma unroll
      for (int ni = 0; ni < 4; ni++)
        acc[mi][ni] = __builtin_amdgcn_mfma_f32_16x16x32_bf16(
            af[mi], bfr[ni], acc[mi][ni], 0, 0, 0);
  }
#pragma unroll
  for (int mi = 0; mi < 2; mi++)
#pragma unroll
    for (int ni = 0; ni < 4; ni++)
#pragma unroll
      for (int r = 0; r < 4; r++) {
        int gr = m0 + wm + mi * 16 + quad * 4 + r;
        int gc = n0 + wn + ni * 16 + fidx;
        C[(size_t)gr * N + gc] = acc[mi][ni][r];
      }
}

// ---------------- MFMA flash attention, FIXED-SHIFT softmax -----------------
// After RMSNorm+RoPE (norm-preserving) and the folded 0.125 scale:
// |q_row|_2 = 1, |k_row|_2 = 8  =>  |score| <= 8 (Cauchy-Schwarz), exactly.
// So softmax uses the constant shift exp(s - 8): mathematically identical to
// max-shifted softmax, no overflow (<= e^0.07 with bf16 slack), no underflow
// (>= e^-16). Eliminates the running-max shfl chains, alpha rescales of O,
// and moves the row-sum reduction out of the chunk loop entirely.
#define FIXMAX 8.0f
#define PST 40  // P row stride: 80 B = 5*16 B, ds_read_b128 aligned
#define OST 72  // O stage row stride: 144 B = 9*16 B, aligned
__global__ __launch_bounds__(256) void attn_mfma(
    const bf16_t* __restrict__ qkv, const bf16_t* __restrict__ vt,
    bf16_t* __restrict__ yb) {
  __shared__ bf16_t plds[4][16 * PST];
  __shared__ bf16_t ob[4][32 * OST];
  const int tid = threadIdx.x, lane = tid & 63, w = tid >> 6;
  const int col = lane & 15, quad = lane >> 4;
  const int q0 = blockIdx.x * 32, g = blockIdx.y, b = blockIdx.z;
  const int h = g * 4 + w;

  bf16x8 qf[2][2];
#pragma unroll
  for (int t = 0; t < 2; t++) {
    const bf16_t* qb =
        qkv + ((size_t)b * S_LEN + q0 + t * 16 + col) * QKV_COLS + h * 64 + quad * 8;
    qf[t][0] = *(const bf16x8*)qb;
    qf[t][1] = *(const bf16x8*)(qb + 32);
  }
  const bf16_t* kbase = qkv + (size_t)b * S_LEN * QKV_COLS + 1024 + g * 64 + quad * 8;
  const bf16_t* vbase = vt + ((size_t)((b * 4 + g) * 64) + col) * S_LEN + quad * 8;

  f32x4 o[2][4] = {};
  float ps[2][4] = {};   // per-lane partial row sums (reduced once, at the end)

  const int c_lo = max(0, (q0 - 255) >> 5);
  const int c_hi = (q0 + 31) >> 5;
  for (int c = c_lo; c <= c_hi; c++) {
    const int k0 = c * 32;
    bf16x8 kf[2][2];
#pragma unroll
    for (int nt = 0; nt < 2; nt++) {
      const bf16_t* kp = kbase + (size_t)(k0 + nt * 16 + col) * QKV_COLS;
      kf[nt][0] = *(const bf16x8*)kp;
      kf[nt][1] = *(const bf16x8*)(kp + 32);
    }
    bf16x8 vf[4];
#pragma unroll
    for (int nt2 = 0; nt2 < 4; nt2++)
      vf[nt2] = *(const bf16x8*)(vbase + (size_t)(nt2 * 16) * S_LEN + k0);

#pragma unroll
    for (int t = 0; t < 2; t++) {
      const int qt0 = q0 + t * 16;
      if (k0 > qt0 + 15) continue;          // fully above diagonal for this tile
      f32x4 s[2];
#pragma unroll
      for (int nt = 0; nt < 2; nt++) {
        f32x4 a = {};
        a = __builtin_amdgcn_mfma_f32_16x16x32_bf16(qf[t][0], kf[nt][0], a, 0, 0, 0);
        a = __builtin_amdgcn_mfma_f32_16x16x32_bf16(qf[t][1], kf[nt][1], a, 0, 0, 0);
        s[nt] = a;
      }
      const bool needmask = (k0 + 31 > qt0) || (k0 < qt0 - 224);  // wave-uniform
      if (needmask) {
#pragma unroll
        for (int r = 0; r < 4; r++) {
          int q = qt0 + quad * 4 + r;
#pragma unroll
          for (int nt = 0; nt < 2; nt++) {
            int k = k0 + nt * 16 + col;
            bool valid = (k <= q) && (q - k < 256);
            float p = valid ? __expf(s[nt][r] - FIXMAX) : 0.f;
            ps[t][r] += p;
            plds[w][(quad * 4 + r) * PST + nt * 16 + col] = (bf16_t)p;
          }
        }
      } else {
#pragma unroll
        for (int r = 0; r < 4; r++) {
#pragma unroll
          for (int nt = 0; nt < 2; nt++) {
            float p = __expf(s[nt][r] - FIXMAX);
            ps[t][r] += p;
            plds[w][(quad * 4 + r) * PST + nt * 16 + col] = (bf16_t)p;
          }
        }
      }
      asm volatile("s_waitcnt lgkmcnt(0)" ::: "memory");
      bf16x8 pf = *(const bf16x8*)(plds[w] + col * PST + quad * 8);
#pragma unroll
      for (int nt2 = 0; nt2 < 4; nt2++)
        o[t][nt2] = __builtin_amdgcn_mfma_f32_16x16x32_bf16(pf, vf[nt2], o[t][nt2], 0, 0, 0);
    }
  }
  // ---- one row-sum reduction, normalize -> wave-local LDS -> coalesced stores
#pragma unroll
  for (int t = 0; t < 2; t++)
#pragma unroll
    for (int r = 0; r < 4; r++) {
      float v = ps[t][r];
#pragma unroll
      for (int off = 8; off >= 1; off >>= 1) v += __shfl_xor(v, off);
      float il = 1.f / v;
      int row = t * 16 + quad * 4 + r;
#pragma unroll
      for (int nt2 = 0; nt2 < 4; nt2++)
        ob[w][row * OST + nt2 * 16 + col] = (bf16_t)(o[t][nt2][r] * il);
    }
  asm volatile("s_waitcnt lgkmcnt(0)" ::: "memory");
#pragma unroll
  for (int it = 0; it < 4; it++) {
    int row = it * 8 + (lane >> 3);       // 0..31
    int d0 = (lane & 7) * 8;
    bf16x8 v8 = *(const bf16x8*)(ob[w] + row * OST + d0);
    *(bf16x8*)(yb + ((size_t)b * S_LEN + q0 + row) * 1024 + h * 64 + d0) = v8;
  }
}

extern "C" void kernel_launch(void* const* d_in, const int* in_sizes, int n_in,
                              void* d_out, int out_size, void* d_ws, size_t ws_size,
                              hipStream_t stream) {
  const float* x        = (const float*)d_in[0];
  const float* Wq       = (const float*)d_in[1];
  const float* Wk       = (const float*)d_in[2];
  const float* Wv       = (const float*)d_in[3];
  const float* Wo       = (const float*)d_in[4];
  const float* q_gain   = (const float*)d_in[5];
  const float* pair_mix = (const float*)d_in[6];
  float* out = (float*)d_out;

  bf16_t* ws    = (bf16_t*)d_ws;
  bf16_t* xb    = ws;                   // 4096*1024
  bf16_t* wqkvb = xb + 4096 * 1024;     // 1536*1024
  bf16_t* wob   = wqkvb + 1536 * 1024;  // 1024*1024 (premixed)
  bf16_t* qkvb  = wob + 1024 * 1024;    // 4096*1536
  bf16_t* yb    = qkvb + 4096 * 1536;   // 4096*1024
  bf16_t* vt    = yb + 4096 * 1024;     // 8*64*2048 (total ~36.7 MB)

  convert_all<<<6656, 256, 0, stream>>>(
      (const float4*)x, (const float4*)Wq, (const float4*)Wk, (const float4*)Wv,
      (const float4*)Wo, pair_mix, (bf16x4*)xb, (bf16x4*)wqkvb, (bf16x4*)wob);
  gemm_qkv<<<dim3(12, 64), 256, 0, stream>>>(xb, wqkvb, qkvb, vt, q_gain, 1536, 1024);
  attn_mfma<<<dim3(64, 4, 2), 256, 0, stream>>>(qkvb, vt, yb);
  gemm_bt_f32<<<dim3(8, 64), 256, 0, stream>>>(yb, wob, out, 1024, 1024);
}

// Round 9
// 144.212 us; speedup vs baseline: 1.4271x; 1.0696x over previous
//
#include <hip/hip_runtime.h>
#include <hip/hip_bf16.h>
#include <cstdint>

// Problem constants (B=2, S=2048, DIM=1024, H=16, KVH=4, HD=64, WINDOW=256)
#define S_LEN 2048
#define QKV_COLS 1536   // 1024 q | 256 k | 256 v

typedef __bf16 bf16_t;
typedef bf16_t bf16x8 __attribute__((ext_vector_type(8)));
typedef bf16_t bf16x4 __attribute__((ext_vector_type(4)));
typedef float f32x4 __attribute__((ext_vector_type(4)));

typedef __attribute__((address_space(1))) void as1_void;
typedef __attribute__((address_space(3))) void as3_void;

__device__ __forceinline__ void async_load16(const void* g, void* lds) {
  __builtin_amdgcn_global_load_lds(
      (as1_void*)(uintptr_t)g,
      (as3_void*)(uint32_t)(uintptr_t)lds,
      16, 0, 0);
}

// ---------------- f32 -> bf16 convert; Wo gets pair_mix premixed ------------
__global__ __launch_bounds__(256) void convert_all(
    const float4* __restrict__ x, const float4* __restrict__ wq,
    const float4* __restrict__ wk, const float4* __restrict__ wv,
    const float4* __restrict__ wo, const float* __restrict__ pm,
    bf16x4* __restrict__ xb, bf16x4* __restrict__ wqkvb, bf16x4* __restrict__ wob) {
  int u = blockIdx.x * 256 + threadIdx.x;
  if (u >= 1441792) {                       // Wo premix region
    int off = u - 1441792;                  // float4 index into 1024x1024
    int flat = off * 4;
    int row = flat >> 10, colf = flat & 1023;
    int col2p = colf & ~64;
    int p = colf >> 7, ii = (colf >> 6) & 1;
    float4 a = wo[(row * 1024 + col2p) >> 2];
    float4 bq = wo[(row * 1024 + (col2p | 64)) >> 2];
    float m0v = pm[p * 4 + ii], m1v = pm[p * 4 + 2 + ii];
    bf16x4 o4;
    o4[0] = (bf16_t)(m0v * a.x + m1v * bq.x);
    o4[1] = (bf16_t)(m0v * a.y + m1v * bq.y);
    o4[2] = (bf16_t)(m0v * a.z + m1v * bq.z);
    o4[3] = (bf16_t)(m0v * a.w + m1v * bq.w);
    wob[off] = o4;
    return;
  }
  const float4* src; bf16x4* dst; int off;
  if (u < 1048576)      { src = x;  dst = xb;             off = u; }
  else if (u < 1310720) { src = wq; dst = wqkvb;          off = u - 1048576; }
  else if (u < 1376256) { src = wk; dst = wqkvb + 262144; off = u - 1310720; }
  else                  { src = wv; dst = wqkvb + 327680; off = u - 1376256; }
  float4 f = src[off];
  bf16x4 o;
  o[0] = (bf16_t)f.x; o[1] = (bf16_t)f.y; o[2] = (bf16_t)f.z; o[3] = (bf16_t)f.w;
  dst[off] = o;
}

// ---------------- QKV GEMM (64x128 tile, BK=64) + norm/rope + V-transpose ---
// LDS rows are 128 B -> XOR-swizzle chunk slots (slot ^ row&7) at staging and
// at fragment reads (legal: swizzle permutes which GLOBAL chunk each lane
// fetches; LDS dest stays base + tid*16 as global_load_lds requires).
__global__ __launch_bounds__(256) void gemm_qkv(
    const bf16_t* __restrict__ A, const bf16_t* __restrict__ B,
    bf16_t* __restrict__ C, bf16_t* __restrict__ vt,
    const float* __restrict__ q_gain, int N, int K) {
  __shared__ bf16_t As[64 * 64];    // 8 KB
  __shared__ bf16_t Bs[128 * 64];   // 16 KB
  const int tid = threadIdx.x;
  const int lane = tid & 63;
  const int w = tid >> 6;
  const int wm = (w & 1) << 5, wn = (w >> 1) << 6;
  const int m0 = blockIdx.y << 6, n0 = blockIdx.x << 7;
  const int fidx = lane & 15, quad = lane >> 4;
  f32x4 acc[2][4] = {};
  int ra0 = (tid + 0) >> 3,   sa0 = ((tid + 0) & 7) ^ (ra0 & 7);
  int ra1 = (tid + 256) >> 3, sa1 = ((tid + 256) & 7) ^ (ra1 & 7);
  const bf16_t* Ag0 = A + (size_t)(m0 + ra0) * K + sa0 * 8;
  const bf16_t* Ag1 = A + (size_t)(m0 + ra1) * K + sa1 * 8;
  const bf16_t* Bg[4];
#pragma unroll
  for (int j = 0; j < 4; j++) {
    int c = tid + j * 256, r = c >> 3, s = (c & 7) ^ (r & 7);
    Bg[j] = B + (size_t)(n0 + r) * K + s * 8;
  }
  int aoff[2][2], boff[4][2];
#pragma unroll
  for (int mi = 0; mi < 2; mi++) {
    int row = wm + mi * 16 + fidx;
#pragma unroll
    for (int half = 0; half < 2; half++)
      aoff[mi][half] = row * 64 + (((half * 4 + quad) ^ (row & 7)) * 8);
  }
#pragma unroll
  for (int ni = 0; ni < 4; ni++) {
    int row = wn + ni * 16 + fidx;
#pragma unroll
    for (int half = 0; half < 2; half++)
      boff[ni][half] = row * 64 + (((half * 4 + quad) ^ (row & 7)) * 8);
  }
  for (int kt = 0; kt < K; kt += 64) {
    __syncthreads();
    async_load16(Ag0 + kt, As + tid * 8);
    async_load16(Ag1 + kt, As + (tid + 256) * 8);
#pragma unroll
    for (int j = 0; j < 4; j++)
      async_load16(Bg[j] + kt, Bs + (tid + j * 256) * 8);
    __syncthreads();
    bf16x8 af[2][2], bfr[4][2];
#pragma unroll
    for (int mi = 0; mi < 2; mi++)
#pragma unroll
      for (int half = 0; half < 2; half++)
        af[mi][half] = *(const bf16x8*)(As + aoff[mi][half]);
#pragma unroll
    for (int ni = 0; ni < 4; ni++)
#pragma unroll
      for (int half = 0; half < 2; half++)
        bfr[ni][half] = *(const bf16x8*)(Bs + boff[ni][half]);
#pragma unroll
    for (int half = 0; half < 2; half++)
#pragma unroll
      for (int mi = 0; mi < 2; mi++)
#pragma unroll
        for (int ni = 0; ni < 4; ni++)
          acc[mi][ni] = __builtin_amdgcn_mfma_f32_16x16x32_bf16(
              af[mi][half], bfr[ni][half], acc[mi][ni], 0, 0, 0);
  }
  const int hc0 = n0 + wn;
  if (hc0 >= 1280) {
    // ---- V: transposed store into vt[(b*4+g)*64+dh][s]
#pragma unroll
    for (int mi = 0; mi < 2; mi++)
#pragma unroll
      for (int ni = 0; ni < 4; ni++) {
        int cg = (hc0 - 1280) + ni * 16 + fidx;
        int g = cg >> 6, dh = cg & 63;
        int srow = m0 + wm + mi * 16 + quad * 4;
        int bb = srow >> 11, si = srow & (S_LEN - 1);
        bf16x4 pack;
#pragma unroll
        for (int r = 0; r < 4; r++) pack[r] = (bf16_t)acc[mi][ni][r];
        *(bf16x4*)(vt + ((size_t)((bb * 4 + g) * 64 + dh)) * S_LEN + si) = pack;
      }
    return;
  }
  // ---- q/k: RMSNorm + RoPE (+gain for q)
  float gain = 1.f;
  if (hc0 < 1024) gain = q_gain[hc0 >> 6] * 0.125f;  // fold softmax scale
#pragma unroll
  for (int mi = 0; mi < 2; mi++)
#pragma unroll
    for (int r = 0; r < 4; r++) {
      float ss = 0.f;
#pragma unroll
      for (int ni = 0; ni < 4; ni++) { float t = acc[mi][ni][r]; ss += t * t; }
#pragma unroll
      for (int off = 8; off >= 1; off >>= 1) ss += __shfl_xor(ss, off);
      float scl = rsqrtf(ss * (1.f / 64.f) + 1e-6f);
      int s = (m0 + wm + mi * 16 + quad * 4 + r) & (S_LEN - 1);
#pragma unroll
      for (int ni = 0; ni < 2; ni++) {
        float v1 = acc[mi][ni][r] * scl;
        float v2 = acc[mi][ni + 2][r] * scl;
        float fr = (float)(ni * 16 + fidx);
        float ang = (float)s * __expf(fr * -0.28782313662425575f);  // ln(1e4)/32
        float sn, cs;
        __sincosf(ang, &sn, &cs);
        acc[mi][ni][r]     = (v1 * cs + v2 * sn) * gain;
        acc[mi][ni + 2][r] = (-v1 * sn + v2 * cs) * gain;
      }
    }
#pragma unroll
  for (int mi = 0; mi < 2; mi++)
#pragma unroll
    for (int ni = 0; ni < 4; ni++)
#pragma unroll
      for (int r = 0; r < 4; r++) {
        int gr = m0 + wm + mi * 16 + quad * 4 + r;
        int gc = n0 + wn + ni * 16 + fidx;
        C[(size_t)gr * N + gc] = (bf16_t)acc[mi][ni][r];
      }
}

// ---------------- out-proj GEMM (64x128 tile, BK=64, f32 out) ---------------
__global__ __launch_bounds__(256) void gemm_bt_f32(
    const bf16_t* __restrict__ A, const bf16_t* __restrict__ B,
    float* __restrict__ C, int N, int K) {
  __shared__ bf16_t As[64 * 64];
  __shared__ bf16_t Bs[128 * 64];
  const int tid = threadIdx.x;
  const int lane = tid & 63;
  const int w = tid >> 6;
  const int wm = (w & 1) << 5, wn = (w >> 1) << 6;
  const int m0 = blockIdx.y << 6, n0 = blockIdx.x << 7;
  const int fidx = lane & 15, quad = lane >> 4;
  f32x4 acc[2][4] = {};
  int ra0 = (tid + 0) >> 3,   sa0 = ((tid + 0) & 7) ^ (ra0 & 7);
  int ra1 = (tid + 256) >> 3, sa1 = ((tid + 256) & 7) ^ (ra1 & 7);
  const bf16_t* Ag0 = A + (size_t)(m0 + ra0) * K + sa0 * 8;
  const bf16_t* Ag1 = A + (size_t)(m0 + ra1) * K + sa1 * 8;
  const bf16_t* Bg[4];
#pragma unroll
  for (int j = 0; j < 4; j++) {
    int c = tid + j * 256, r = c >> 3, s = (c & 7) ^ (r & 7);
    Bg[j] = B + (size_t)(n0 + r) * K + s * 8;
  }
  int aoff[2][2], boff[4][2];
#pragma unroll
  for (int mi = 0; mi < 2; mi++) {
    int row = wm + mi * 16 + fidx;
#pragma unroll
    for (int half = 0; half < 2; half++)
      aoff[mi][half] = row * 64 + (((half * 4 + quad) ^ (row & 7)) * 8);
  }
#pragma unroll
  for (int ni = 0; ni < 4; ni++) {
    int row = wn + ni * 16 + fidx;
#pragma unroll
    for (int half = 0; half < 2; half++)
      boff[ni][half] = row * 64 + (((half * 4 + quad) ^ (row & 7)) * 8);
  }
  for (int kt = 0; kt < K; kt += 64) {
    __syncthreads();
    async_load16(Ag0 + kt, As + tid * 8);
    async_load16(Ag1 + kt, As + (tid + 256) * 8);
#pragma unroll
    for (int j = 0; j < 4; j++)
      async_load16(Bg[j] + kt, Bs + (tid + j * 256) * 8);
    __syncthreads();
    bf16x8 af[2][2], bfr[4][2];
#pragma unroll
    for (int mi = 0; mi < 2; mi++)
#pragma unroll
      for (int half = 0; half < 2; half++)
        af[mi][half] = *(const bf16x8*)(As + aoff[mi][half]);
#pragma unroll
    for (int ni = 0; ni < 4; ni++)
#pragma unroll
      for (int half = 0; half < 2; half++)
        bfr[ni][half] = *(const bf16x8*)(Bs + boff[ni][half]);
#pragma unroll
    for (int half = 0; half < 2; half++)
#pragma unroll
      for (int mi = 0; mi < 2; mi++)
#pragma unroll
        for (int ni = 0; ni < 4; ni++)
          acc[mi][ni] = __builtin_amdgcn_mfma_f32_16x16x32_bf16(
              af[mi][half], bfr[ni][half], acc[mi][ni], 0, 0, 0);
  }
#pragma unroll
  for (int mi = 0; mi < 2; mi++)
#pragma unroll
    for (int ni = 0; ni < 4; ni++)
#pragma unroll
      for (int r = 0; r < 4; r++) {
        int gr = m0 + wm + mi * 16 + quad * 4 + r;
        int gc = n0 + wn + ni * 16 + fidx;
        C[(size_t)gr * N + gc] = acc[mi][ni][r];
      }
}

// ---------------- MFMA flash attention, FIXED-SHIFT softmax (R7, verified) --
// |q_row|_2 = 1, |k_row|_2 = 8 after norm (RoPE is norm-preserving), so
// |score| <= 8 exactly; softmax uses constant shift exp(s-8).
#define FIXMAX 8.0f
#define PST 40  // P row stride: 80 B = 5*16 B, ds_read_b128 aligned
#define OST 72  // O stage row stride: 144 B = 9*16 B, aligned
__global__ __launch_bounds__(256) void attn_mfma(
    const bf16_t* __restrict__ qkv, const bf16_t* __restrict__ vt,
    bf16_t* __restrict__ yb) {
  __shared__ bf16_t plds[4][16 * PST];
  __shared__ bf16_t ob[4][32 * OST];
  const int tid = threadIdx.x, lane = tid & 63, w = tid >> 6;
  const int col = lane & 15, quad = lane >> 4;
  const int q0 = blockIdx.x * 32, g = blockIdx.y, b = blockIdx.z;
  const int h = g * 4 + w;

  bf16x8 qf[2][2];
#pragma unroll
  for (int t = 0; t < 2; t++) {
    const bf16_t* qb =
        qkv + ((size_t)b * S_LEN + q0 + t * 16 + col) * QKV_COLS + h * 64 + quad * 8;
    qf[t][0] = *(const bf16x8*)qb;
    qf[t][1] = *(const bf16x8*)(qb + 32);
  }
  const bf16_t* kbase = qkv + (size_t)b * S_LEN * QKV_COLS + 1024 + g * 64 + quad * 8;
  const bf16_t* vbase = vt + ((size_t)((b * 4 + g) * 64) + col) * S_LEN + quad * 8;

  f32x4 o[2][4] = {};
  float ps[2][4] = {};   // per-lane partial row sums (reduced once, at the end)

  const int c_lo = max(0, (q0 - 255) >> 5);
  const int c_hi = (q0 + 31) >> 5;
  for (int c = c_lo; c <= c_hi; c++) {
    const int k0 = c * 32;
    bf16x8 kf[2][2];
#pragma unroll
    for (int nt = 0; nt < 2; nt++) {
      const bf16_t* kp = kbase + (size_t)(k0 + nt * 16 + col) * QKV_COLS;
      kf[nt][0] = *(const bf16x8*)kp;
      kf[nt][1] = *(const bf16x8*)(kp + 32);
    }
    bf16x8 vf[4];
#pragma unroll
    for (int nt2 = 0; nt2 < 4; nt2++)
      vf[nt2] = *(const bf16x8*)(vbase + (size_t)(nt2 * 16) * S_LEN + k0);

#pragma unroll
    for (int t = 0; t < 2; t++) {
      const int qt0 = q0 + t * 16;
      if (k0 > qt0 + 15) continue;          // fully above diagonal for this tile
      f32x4 s[2];
#pragma unroll
      for (int nt = 0; nt < 2; nt++) {
        f32x4 a = {};
        a = __builtin_amdgcn_mfma_f32_16x16x32_bf16(qf[t][0], kf[nt][0], a, 0, 0, 0);
        a = __builtin_amdgcn_mfma_f32_16x16x32_bf16(qf[t][1], kf[nt][1], a, 0, 0, 0);
        s[nt] = a;
      }
      const bool needmask = (k0 + 31 > qt0) || (k0 < qt0 - 224);  // wave-uniform
      if (needmask) {
#pragma unroll
        for (int r = 0; r < 4; r++) {
          int q = qt0 + quad * 4 + r;
#pragma unroll
          for (int nt = 0; nt < 2; nt++) {
            int k = k0 + nt * 16 + col;
            bool valid = (k <= q) && (q - k < 256);
            float p = valid ? __expf(s[nt][r] - FIXMAX) : 0.f;
            ps[t][r] += p;
            plds[w][(quad * 4 + r) * PST + nt * 16 + col] = (bf16_t)p;
          }
        }
      } else {
#pragma unroll
        for (int r = 0; r < 4; r++) {
#pragma unroll
          for (int nt = 0; nt < 2; nt++) {
            float p = __expf(s[nt][r] - FIXMAX);
            ps[t][r] += p;
            plds[w][(quad * 4 + r) * PST + nt * 16 + col] = (bf16_t)p;
          }
        }
      }
      asm volatile("s_waitcnt lgkmcnt(0)" ::: "memory");
      bf16x8 pf = *(const bf16x8*)(plds[w] + col * PST + quad * 8);
#pragma unroll
      for (int nt2 = 0; nt2 < 4; nt2++)
        o[t][nt2] = __builtin_amdgcn_mfma_f32_16x16x32_bf16(pf, vf[nt2], o[t][nt2], 0, 0, 0);
    }
  }
  // ---- one row-sum reduction, normalize -> wave-local LDS -> coalesced stores
#pragma unroll
  for (int t = 0; t < 2; t++)
#pragma unroll
    for (int r = 0; r < 4; r++) {
      float v = ps[t][r];
#pragma unroll
      for (int off = 8; off >= 1; off >>= 1) v += __shfl_xor(v, off);
      float il = 1.f / v;
      int row = t * 16 + quad * 4 + r;
#pragma unroll
      for (int nt2 = 0; nt2 < 4; nt2++)
        ob[w][row * OST + nt2 * 16 + col] = (bf16_t)(o[t][nt2][r] * il);
    }
  asm volatile("s_waitcnt lgkmcnt(0)" ::: "memory");
#pragma unroll
  for (int it = 0; it < 4; it++) {
    int row = it * 8 + (lane >> 3);       // 0..31
    int d0 = (lane & 7) * 8;
    bf16x8 v8 = *(const bf16x8*)(ob[w] + row * OST + d0);
    *(bf16x8*)(yb + ((size_t)b * S_LEN + q0 + row) * 1024 + h * 64 + d0) = v8;
  }
}

extern "C" void kernel_launch(void* const* d_in, const int* in_sizes, int n_in,
                              void* d_out, int out_size, void* d_ws, size_t ws_size,
                              hipStream_t stream) {
  const float* x        = (const float*)d_in[0];
  const float* Wq       = (const float*)d_in[1];
  const float* Wk       = (const float*)d_in[2];
  const float* Wv       = (const float*)d_in[3];
  const float* Wo       = (const float*)d_in[4];
  const float* q_gain   = (const float*)d_in[5];
  const float* pair_mix = (const float*)d_in[6];
  float* out = (float*)d_out;

  bf16_t* ws    = (bf16_t*)d_ws;
  bf16_t* xb    = ws;                   // 4096*1024
  bf16_t* wqkvb = xb + 4096 * 1024;     // 1536*1024
  bf16_t* wob   = wqkvb + 1536 * 1024;  // 1024*1024 (premixed)
  bf16_t* qkvb  = wob + 1024 * 1024;    // 4096*1536
  bf16_t* yb    = qkvb + 4096 * 1536;   // 4096*1024
  bf16_t* vt    = yb + 4096 * 1024;     // 8*64*2048 (total ~36.7 MB)

  convert_all<<<6656, 256, 0, stream>>>(
      (const float4*)x, (const float4*)Wq, (const float4*)Wk, (const float4*)Wv,
      (const float4*)Wo, pair_mix, (bf16x4*)xb, (bf16x4*)wqkvb, (bf16x4*)wob);
  gemm_qkv<<<dim3(12, 64), 256, 0, stream>>>(xb, wqkvb, qkvb, vt, q_gain, 1536, 1024);
  attn_mfma<<<dim3(64, 4, 2), 256, 0, stream>>>(qkvb, vt, yb);
  gemm_bt_f32<<<dim3(8, 64), 256, 0, stream>>>(yb, wob, out, 1024, 1024);
}